// Round 1
// baseline (876.547 us; speedup 1.0000x reference)
//
#include <hip/hip_runtime.h>

#define N_NODES 50000
#define N_EDGES 800000
#define N_OBS   4
#define HID     64
#define K_HOPS  5
#define ROW     (N_OBS * HID)   // 256 floats per node

// ---------------------------------------------------------------- zero
__global__ void zero_kernel(int* __restrict__ p, int n) {
    int i = blockIdx.x * blockDim.x + threadIdx.x;
    if (i < n) p[i] = 0;
}

// ---------------------------------------------------------------- histogram of dst
__global__ void hist_kernel(const int* __restrict__ dst, int* __restrict__ cnt) {
    int e = blockIdx.x * blockDim.x + threadIdx.x;
    if (e < N_EDGES) atomicAdd(&cnt[dst[e]], 1);
}

// ---------------------------------------------------------------- exclusive scan (1 block, 1024 thr)
__global__ __launch_bounds__(1024) void scan_kernel(const int* __restrict__ counts,
                                                    int* __restrict__ offsets,
                                                    int* __restrict__ cursor) {
    __shared__ int wsum[16];
    __shared__ int wpre[16];
    __shared__ int s_run;
    const int t = threadIdx.x, lane = t & 63, wid = t >> 6;
    if (t == 0) { s_run = 0; offsets[0] = 0; }
    __syncthreads();
    for (int base = 0; base < N_NODES; base += 1024) {
        int i = base + t;
        int v = (i < N_NODES) ? counts[i] : 0;
        int x = v;
        // inclusive wave scan
        #pragma unroll
        for (int off = 1; off < 64; off <<= 1) {
            int y = __shfl_up(x, off);
            if (lane >= off) x += y;
        }
        if (lane == 63) wsum[wid] = x;
        __syncthreads();
        if (t < 16) {
            int p = 0;
            for (int j = 0; j < t; ++j) p += wsum[j];
            wpre[t] = p;
        }
        __syncthreads();
        int incl = x + wpre[wid];
        int run = s_run;
        if (i < N_NODES) {
            offsets[i + 1] = run + incl;
            cursor[i]      = run + incl - v;   // exclusive
        }
        __syncthreads();
        if (t == 1023) s_run = run + incl;
        __syncthreads();
    }
}

// ---------------------------------------------------------------- scatter edges into CSR order
__global__ void scatter_kernel(const int* __restrict__ src, const int* __restrict__ dst,
                               const float* __restrict__ w, int* __restrict__ cursor,
                               int* __restrict__ ssrc, float* __restrict__ sw) {
    int e = blockIdx.x * blockDim.x + threadIdx.x;
    if (e < N_EDGES) {
        int d = dst[e];
        int p = atomicAdd(&cursor[d], 1);
        ssrc[p] = src[e];
        sw[p]   = w[e];
    }
}

// ---------------------------------------------------------------- lift: X[n,o,h] = nodes[n,o]*Wl[h] + bl[h]
__global__ void lift_kernel(const float* __restrict__ nodes, const float* __restrict__ Wl,
                            const float* __restrict__ bl, float* __restrict__ X) {
    int i = blockIdx.x * blockDim.x + threadIdx.x;   // over N*O*HID/4 float4s
    const int total = N_NODES * ROW / 4;
    if (i >= total) return;
    int h4 = i & 15;     // float4 index within h-dim
    int no = i >> 4;     // n*4 + o
    float s = nodes[no];
    float4 wl = ((const float4*)Wl)[h4];
    float4 b  = ((const float4*)bl)[h4];
    float4 r;
    r.x = s * wl.x + b.x; r.y = s * wl.y + b.y;
    r.z = s * wl.z + b.z; r.w = s * wl.w + b.w;
    ((float4*)X)[i] = r;
}

// ---------------------------------------------------------------- aggregate: one wave per dst node
__global__ __launch_bounds__(256) void agg_kernel(const int* __restrict__ offsets,
                                                  const int* __restrict__ ssrc,
                                                  const float* __restrict__ sw,
                                                  const float* __restrict__ X,
                                                  float* __restrict__ agg) {
    int wave = (blockIdx.x * blockDim.x + threadIdx.x) >> 6;
    int lane = threadIdx.x & 63;
    if (wave >= N_NODES) return;
    int s = offsets[wave], e = offsets[wave + 1];
    float4 acc0 = {0.f, 0.f, 0.f, 0.f};
    float4 acc1 = {0.f, 0.f, 0.f, 0.f};
    int i = s;
    for (; i + 1 < e; i += 2) {
        int s0 = ssrc[i], s1 = ssrc[i + 1];
        float w0 = sw[i], w1 = sw[i + 1];
        float4 x0 = ((const float4*)(X + (size_t)s0 * ROW))[lane];
        float4 x1 = ((const float4*)(X + (size_t)s1 * ROW))[lane];
        acc0.x += w0 * x0.x; acc0.y += w0 * x0.y; acc0.z += w0 * x0.z; acc0.w += w0 * x0.w;
        acc1.x += w1 * x1.x; acc1.y += w1 * x1.y; acc1.z += w1 * x1.z; acc1.w += w1 * x1.w;
    }
    if (i < e) {
        int s0 = ssrc[i];
        float w0 = sw[i];
        float4 x0 = ((const float4*)(X + (size_t)s0 * ROW))[lane];
        acc0.x += w0 * x0.x; acc0.y += w0 * x0.y; acc0.z += w0 * x0.z; acc0.w += w0 * x0.w;
    }
    float4 r;
    r.x = acc0.x + acc1.x; r.y = acc0.y + acc1.y;
    r.z = acc0.z + acc1.z; r.w = acc0.w + acc1.w;
    ((float4*)(agg + (size_t)wave * ROW))[lane] = r;
}

// ---------------------------------------------------------------- Y = relu(A @ W + b), A:(200000,64) W:(64,64)
// In-place safe (A tile staged to LDS before any write to Y).
__global__ __launch_bounds__(256) void mm_relu_kernel(const float* __restrict__ A,
                                                      const float* __restrict__ W,
                                                      const float* __restrict__ bias,
                                                      float* __restrict__ Y) {
    __shared__ float As[64][65];
    __shared__ float Ws[64][64];
    __shared__ float bs[64];
    const int t = threadIdx.x;
    const long rowBase = (long)blockIdx.x * 64;
    for (int f = t; f < 1024; f += 256) {
        int r = f >> 4, c4 = f & 15;
        float4 v = ((const float4*)(A + (rowBase + r) * 64))[c4];
        As[r][c4 * 4 + 0] = v.x; As[r][c4 * 4 + 1] = v.y;
        As[r][c4 * 4 + 2] = v.z; As[r][c4 * 4 + 3] = v.w;
        float4 wv = ((const float4*)(W + r * 64))[c4];
        ((float4*)(&Ws[r][0]))[c4] = wv;
    }
    if (t < 16) ((float4*)bs)[t] = ((const float4*)bias)[t];
    __syncthreads();
    const int rg = t >> 4, cg = t & 15;
    float acc[4][4] = {{0.f}};
    #pragma unroll 8
    for (int k = 0; k < 64; ++k) {
        float a0 = As[rg * 4 + 0][k];
        float a1 = As[rg * 4 + 1][k];
        float a2 = As[rg * 4 + 2][k];
        float a3 = As[rg * 4 + 3][k];
        float4 wv = ((const float4*)(&Ws[k][0]))[cg];
        acc[0][0] += a0 * wv.x; acc[0][1] += a0 * wv.y; acc[0][2] += a0 * wv.z; acc[0][3] += a0 * wv.w;
        acc[1][0] += a1 * wv.x; acc[1][1] += a1 * wv.y; acc[1][2] += a1 * wv.z; acc[1][3] += a1 * wv.w;
        acc[2][0] += a2 * wv.x; acc[2][1] += a2 * wv.y; acc[2][2] += a2 * wv.z; acc[2][3] += a2 * wv.w;
        acc[3][0] += a3 * wv.x; acc[3][1] += a3 * wv.y; acc[3][2] += a3 * wv.z; acc[3][3] += a3 * wv.w;
    }
    float4 bv = ((const float4*)bs)[cg];
    #pragma unroll
    for (int i2 = 0; i2 < 4; ++i2) {
        float4 o;
        o.x = fmaxf(acc[i2][0] + bv.x, 0.f);
        o.y = fmaxf(acc[i2][1] + bv.y, 0.f);
        o.z = fmaxf(acc[i2][2] + bv.z, 0.f);
        o.w = fmaxf(acc[i2][3] + bv.w, 0.f);
        ((float4*)(Y + (rowBase + rg * 4 + i2) * 64))[cg] = o;
    }
}

// ---------------------------------------------------------------- launch
extern "C" void kernel_launch(void* const* d_in, const int* in_sizes, int n_in,
                              void* d_out, int out_size, void* d_ws, size_t ws_size,
                              hipStream_t stream) {
    const float* nodes   = (const float*)d_in[0];
    const int*   esrc    = (const int*)d_in[1];
    const int*   edst    = (const int*)d_in[2];
    const float* eweight = (const float*)d_in[3];
    const float* W_lift  = (const float*)d_in[4];
    const float* b_lift  = (const float*)d_in[5];
    const float* W_hop   = (const float*)d_in[6];
    const float* b_hop   = (const float*)d_in[7];

    char* ws = (char*)d_ws;
    float* X    = (float*)(ws);                        // 51,200,000 B
    int*   SSRC = (int*)  (ws + 51200000);             //  3,200,000 B
    float* SW   = (float*)(ws + 54400000);             //  3,200,000 B
    int*   OFF  = (int*)  (ws + 57600000);             //    200,064 B (50001 ints)
    int*   CUR  = (int*)  (ws + 57800064);             //    200,000 B
    int*   CNT  = (int*)  (ws + 58000064);             //    200,000 B
    float* AGG  = (float*)d_out;                       // reuse output buffer as agg scratch

    // CSR build
    zero_kernel<<<(N_NODES + 255) / 256, 256, 0, stream>>>(CNT, N_NODES);
    hist_kernel<<<(N_EDGES + 255) / 256, 256, 0, stream>>>(edst, CNT);
    scan_kernel<<<1, 1024, 0, stream>>>(CNT, OFF, CUR);
    scatter_kernel<<<(N_EDGES + 255) / 256, 256, 0, stream>>>(esrc, edst, eweight, CUR, SSRC, SW);

    // lift
    lift_kernel<<<(N_NODES * ROW / 4 + 255) / 256, 256, 0, stream>>>(nodes, W_lift, b_lift, X);

    // hops
    const int aggGrid = (N_NODES * 64 + 255) / 256;       // one wave per node
    const int mmGrid  = (N_NODES * N_OBS) / 64;           // 64 rows per block = 3125
    for (int hop = 0; hop < K_HOPS; ++hop) {
        agg_kernel<<<aggGrid, 256, 0, stream>>>(OFF, SSRC, SW, X, AGG);
        float* dstX = (hop == K_HOPS - 1) ? (float*)d_out : X;
        mm_relu_kernel<<<mmGrid, 256, 0, stream>>>(AGG, W_hop, b_hop, dstX);
    }
}

// Round 2
// 630.022 us; speedup vs baseline: 1.3913x; 1.3913x over previous
//
#include <hip/hip_runtime.h>
#include <hip/hip_fp16.h>

#define N_NODES 50000
#define N_EDGES 800000
#define N_OBS   4
#define HID     64
#define K_HOPS  5
#define ROW     (N_OBS * HID)   // 256 elements per node

// ---------------------------------------------------------------- zero
__global__ void zero_kernel(int* __restrict__ p, int n) {
    int i = blockIdx.x * blockDim.x + threadIdx.x;
    if (i < n) p[i] = 0;
}

// ---------------------------------------------------------------- histogram of dst
__global__ void hist_kernel(const int* __restrict__ dst, int* __restrict__ cnt) {
    int e = blockIdx.x * blockDim.x + threadIdx.x;
    if (e < N_EDGES) atomicAdd(&cnt[dst[e]], 1);
}

// ---------------------------------------------------------------- exclusive scan (1 block, 1024 thr)
__global__ __launch_bounds__(1024) void scan_kernel(const int* __restrict__ counts,
                                                    int* __restrict__ offsets,
                                                    int* __restrict__ cursor) {
    __shared__ int wsum[16];
    __shared__ int wpre[16];
    __shared__ int s_run;
    const int t = threadIdx.x, lane = t & 63, wid = t >> 6;
    if (t == 0) { s_run = 0; offsets[0] = 0; }
    __syncthreads();
    for (int base = 0; base < N_NODES; base += 1024) {
        int i = base + t;
        int v = (i < N_NODES) ? counts[i] : 0;
        int x = v;
        #pragma unroll
        for (int off = 1; off < 64; off <<= 1) {
            int y = __shfl_up(x, off);
            if (lane >= off) x += y;
        }
        if (lane == 63) wsum[wid] = x;
        __syncthreads();
        if (t < 16) {
            int p = 0;
            for (int j = 0; j < t; ++j) p += wsum[j];
            wpre[t] = p;
        }
        __syncthreads();
        int incl = x + wpre[wid];
        int run = s_run;
        if (i < N_NODES) {
            offsets[i + 1] = run + incl;
            cursor[i]      = run + incl - v;   // exclusive
        }
        __syncthreads();
        if (t == 1023) s_run = run + incl;
        __syncthreads();
    }
}

// ---------------------------------------------------------------- scatter edges into CSR order
__global__ void scatter_kernel(const int* __restrict__ src, const int* __restrict__ dst,
                               const float* __restrict__ w, int* __restrict__ cursor,
                               int* __restrict__ ssrc, float* __restrict__ sw) {
    int e = blockIdx.x * blockDim.x + threadIdx.x;
    if (e < N_EDGES) {
        int d = dst[e];
        int p = atomicAdd(&cursor[d], 1);
        ssrc[p] = src[e];
        sw[p]   = w[e];
    }
}

// ---------------------------------------------------------------- lift: X[n,o,h] = f16(nodes[n,o]*Wl[h] + bl[h])
__global__ void lift_kernel(const float* __restrict__ nodes, const float* __restrict__ Wl,
                            const float* __restrict__ bl, __half* __restrict__ X) {
    int i = blockIdx.x * blockDim.x + threadIdx.x;   // over N*ROW/4 groups of 4 elems
    const int total = N_NODES * ROW / 4;
    if (i >= total) return;
    int h4 = i & 15;     // float4 index within h-dim
    int no = i >> 4;     // n*4 + o
    float s = nodes[no];
    float4 wl = ((const float4*)Wl)[h4];
    float4 b  = ((const float4*)bl)[h4];
    __half2 lo = __float22half2_rn(make_float2(s * wl.x + b.x, s * wl.y + b.y));
    __half2 hi = __float22half2_rn(make_float2(s * wl.z + b.z, s * wl.w + b.w));
    float2 st;
    *(__half2*)&st.x = lo;
    *(__half2*)&st.y = hi;
    ((float2*)X)[i] = st;
}

// ---------------------------------------------------------------- fused hop:
// one wave per dst node: gather+weight-sum over in-edges (f16 X rows),
// then per-wave 4x64 @ 64x64 GEMM + bias + ReLU from LDS-staged W.
template<int LAST>
__global__ __launch_bounds__(256) void hop_kernel(const int* __restrict__ offsets,
                                                  const int* __restrict__ ssrc,
                                                  const float* __restrict__ sw,
                                                  const __half* __restrict__ Xin,
                                                  const float* __restrict__ W,
                                                  const float* __restrict__ bias,
                                                  __half* __restrict__ Xout,
                                                  float* __restrict__ Fout) {
    __shared__ float Ws[64][64];     // 16 KB, block-shared
    __shared__ float As[4][4][65];   // per-wave agg row, padded (conflict-free)
    __shared__ float bs[64];
    const int t = threadIdx.x;
    const int wid = t >> 6, lane = t & 63;

    // stage W + bias (overlaps with the gather below; barrier before GEMM)
    for (int f = t; f < 1024; f += 256)
        ((float4*)Ws)[f] = ((const float4*)W)[f];
    if (t < 16) ((float4*)bs)[t] = ((const float4*)bias)[t];

    const int node = blockIdx.x * 4 + wid;   // 12500 * 4 == 50000 exactly
    const int s = offsets[node], e = offsets[node + 1];

    float4 acc0 = {0.f, 0.f, 0.f, 0.f};
    float4 acc1 = {0.f, 0.f, 0.f, 0.f};
    int i = s;
    for (; i + 1 < e; i += 2) {
        int s0 = ssrc[i], s1 = ssrc[i + 1];
        float w0 = sw[i], w1 = sw[i + 1];
        float2 v0 = ((const float2*)(Xin + (size_t)s0 * ROW))[lane];
        float2 v1 = ((const float2*)(Xin + (size_t)s1 * ROW))[lane];
        float2 a0 = __half22float2(*(__half2*)&v0.x);
        float2 b0 = __half22float2(*(__half2*)&v0.y);
        float2 a1 = __half22float2(*(__half2*)&v1.x);
        float2 b1 = __half22float2(*(__half2*)&v1.y);
        acc0.x += w0 * a0.x; acc0.y += w0 * a0.y; acc0.z += w0 * b0.x; acc0.w += w0 * b0.y;
        acc1.x += w1 * a1.x; acc1.y += w1 * a1.y; acc1.z += w1 * b1.x; acc1.w += w1 * b1.y;
    }
    if (i < e) {
        int s0 = ssrc[i];
        float w0 = sw[i];
        float2 v0 = ((const float2*)(Xin + (size_t)s0 * ROW))[lane];
        float2 a0 = __half22float2(*(__half2*)&v0.x);
        float2 b0 = __half22float2(*(__half2*)&v0.y);
        acc0.x += w0 * a0.x; acc0.y += w0 * a0.y; acc0.z += w0 * b0.x; acc0.w += w0 * b0.y;
    }
    acc0.x += acc1.x; acc0.y += acc1.y; acc0.z += acc1.z; acc0.w += acc1.w;

    __syncthreads();   // Ws/bs staged

    // park agg row: lane holds elements (o = lane>>4, k = (lane&15)*4 + j)
    const int o = lane >> 4, h4 = lane & 15;
    As[wid][o][h4 * 4 + 0] = acc0.x;
    As[wid][o][h4 * 4 + 1] = acc0.y;
    As[wid][o][h4 * 4 + 2] = acc0.z;
    As[wid][o][h4 * 4 + 3] = acc0.w;

    // wave-local GEMM: out[o][h4*4+j] = sum_k As[wid][o][k] * Ws[k][h4*4+j]
    float r0 = 0.f, r1 = 0.f, r2 = 0.f, r3 = 0.f;
    #pragma unroll 16
    for (int k = 0; k < 64; ++k) {
        float a = As[wid][o][k];
        float4 wv = *(const float4*)&Ws[k][h4 * 4];
        r0 += a * wv.x; r1 += a * wv.y; r2 += a * wv.z; r3 += a * wv.w;
    }
    float4 bv = *(const float4*)&bs[h4 * 4];
    r0 = fmaxf(r0 + bv.x, 0.f);
    r1 = fmaxf(r1 + bv.y, 0.f);
    r2 = fmaxf(r2 + bv.z, 0.f);
    r3 = fmaxf(r3 + bv.w, 0.f);

    if (LAST) {
        float4 ov = {r0, r1, r2, r3};
        ((float4*)(Fout + (size_t)node * ROW))[lane] = ov;
    } else {
        __half2 lo = __float22half2_rn(make_float2(r0, r1));
        __half2 hi = __float22half2_rn(make_float2(r2, r3));
        float2 st;
        *(__half2*)&st.x = lo;
        *(__half2*)&st.y = hi;
        ((float2*)(Xout + (size_t)node * ROW))[lane] = st;
    }
}

// ---------------------------------------------------------------- launch
extern "C" void kernel_launch(void* const* d_in, const int* in_sizes, int n_in,
                              void* d_out, int out_size, void* d_ws, size_t ws_size,
                              hipStream_t stream) {
    const float* nodes   = (const float*)d_in[0];
    const int*   esrc    = (const int*)d_in[1];
    const int*   edst    = (const int*)d_in[2];
    const float* eweight = (const float*)d_in[3];
    const float* W_lift  = (const float*)d_in[4];
    const float* b_lift  = (const float*)d_in[5];
    const float* W_hop   = (const float*)d_in[6];
    const float* b_hop   = (const float*)d_in[7];

    char* ws = (char*)d_ws;
    __half* X0  = (__half*)(ws);                       // 25,600,000 B
    __half* X1  = (__half*)(ws + 25600000);            // 25,600,000 B
    int*   SSRC = (int*)  (ws + 51200000);             //  3,200,000 B
    float* SW   = (float*)(ws + 54400000);             //  3,200,000 B
    int*   OFF  = (int*)  (ws + 57600000);             //    200,064 B (50001 ints)
    int*   CUR  = (int*)  (ws + 57800064);             //    200,000 B
    int*   CNT  = (int*)  (ws + 58000064);             //    200,000 B

    // CSR build
    zero_kernel<<<(N_NODES + 255) / 256, 256, 0, stream>>>(CNT, N_NODES);
    hist_kernel<<<(N_EDGES + 255) / 256, 256, 0, stream>>>(edst, CNT);
    scan_kernel<<<1, 1024, 0, stream>>>(CNT, OFF, CUR);
    scatter_kernel<<<(N_EDGES + 255) / 256, 256, 0, stream>>>(esrc, edst, eweight, CUR, SSRC, SW);

    // lift -> f16 X0
    lift_kernel<<<(N_NODES * ROW / 4 + 255) / 256, 256, 0, stream>>>(nodes, W_lift, b_lift, X0);

    // fused hops, double-buffered f16 X
    const int hopGrid = N_NODES / 4;   // 12500 blocks, 4 waves/block, 1 node/wave
    __half* Xi = X0;
    __half* Xo = X1;
    for (int hop = 0; hop < K_HOPS; ++hop) {
        if (hop == K_HOPS - 1) {
            hop_kernel<1><<<hopGrid, 256, 0, stream>>>(OFF, SSRC, SW, Xi, W_hop, b_hop,
                                                       nullptr, (float*)d_out);
        } else {
            hop_kernel<0><<<hopGrid, 256, 0, stream>>>(OFF, SSRC, SW, Xi, W_hop, b_hop,
                                                       Xo, nullptr);
        }
        __half* tmp = Xi; Xi = Xo; Xo = tmp;
    }
}